// Round 12
// baseline (36.844 us; speedup 1.0000x reference)
//
#include <hip/hip_runtime.h>
#include <math.h>
#include <stdint.h>

// NonLinearLayer: piecewise-quadratic CDF flow on a geometric mesh.
// x:(N,16) f32, pdj:(N,1), sldj:(N,1), log_p:(63,16), mesh_norm:(65,), elmt_size:(64,)
// out = concat(x_out (N*16), pdj_out (N), sldj_out (N))
//
// R12: single kernel (R11's split lost 3us to dispatch serialization), R8
// setup, and a STRAIGHT-LINE fast path: npairs == 4*tpg exactly for this
// problem, so the 4 grid-stride tiles are fully unrolled, all 12 global loads
// issued as one block followed by sched_barrier(0) (loads cannot sink past
// it; compiler owns the registers and inserts correct waitcnts — no R10-style
// asm-pinning hazard). Goal: >=2 tiles of reads genuinely in flight per wave
// (the one config R5-R10 never achieved). Decisive counter: VGPR >= 90.

namespace {
constexpr int DIM = 16;
constexpr int ME  = 64;
constexpr float BOUNDF = 50.0f;
// K1 = 0.2/one_step = 0.02*(1.2^32-1);  INV_L2R = 1/log2(1.2)
constexpr float K1      = 6.8164378f;
constexpr float INV_L2R = 3.8017840f;
constexpr int NBIN = 66;                        // sentinel 0, real 1..64, sentinel 65
constexpr int ROWF = 68;                        // floats per row: 16 dims * 4 + pad
constexpr int COEF_FLOATS = NBIN * ROWF;        // 4488
constexpr int EP_BASE = COEF_FLOATS - 63 * DIM; // transient exp(log_p) scratch
}

__global__ __launch_bounds__(256) void nll_kernel(
    const float* __restrict__ x,
    const float* __restrict__ pdj,
    const float* __restrict__ sldj,
    const float* __restrict__ log_p,
    const float* __restrict__ mesh_norm,
    float* __restrict__ out,
    int npts, int npairs)
{
  __shared__ __align__(16) float co[COEF_FLOATS];
  __shared__ float s_mesh[ME + 1];

  const int tid = threadIdx.x;

  // ---- setup 1: parallel loads + exp ----
  if (tid <= ME) s_mesh[tid] = mesh_norm[tid];
  for (int i = tid; i < 63 * DIM; i += 256)
    co[EP_BASE + i] = __expf(log_p[i]);
  __syncthreads();

  // ---- setup 2a: stash ep columns in regs (scratch overwritten in 2b) ----
  const int wv = tid >> 6, lane = tid & 63;
  float epv[4];
#pragma unroll
  for (int i = 0; i < 4; ++i)
    epv[i] = (lane < 63) ? co[EP_BASE + lane * DIM + (4 * wv + i)] : 0.f;
  const float mj  = s_mesh[lane];
  const float mj1 = s_mesh[lane + 1];
  const float mj2 = s_mesh[(lane + 2 > ME) ? ME : (lane + 2)];
  const float es0 = s_mesh[1] - s_mesh[0];
  __syncthreads();

  // ---- setup 2b: wave-parallel normalize + prefix scan, 4 dims/wave.
  //      lane l writes table row l+1 (row = searchsorted k). ----
  const float h = mj1 - mj;
#pragma unroll
  for (int i = 0; i < 4; ++i) {
    const int d = 4 * wv + i;
    const float ep = epv[i];
    float ss = (lane < 63) ? ep * (mj2 - mj) : 0.f;
    ss += __shfl_xor(ss, 1);  ss += __shfl_xor(ss, 2);  ss += __shfl_xor(ss, 4);
    ss += __shfl_xor(ss, 8);  ss += __shfl_xor(ss, 16); ss += __shfl_xor(ss, 32);
    const float scale = (1.0f - es0) / (0.5f * ss);
    const float cur = (lane < 63) ? ep * scale : 1.0f;   // pdf_norm[lane+1]
    float prev = __shfl_up(cur, 1);                       // pdf_norm[lane]
    if (lane == 0) prev = 1.0f;
    const float cell = (prev + cur) * 0.5f * h;
    float v = cell, o;
    o = __shfl_up(v, 1);  if (lane >= 1)  v += o;
    o = __shfl_up(v, 2);  if (lane >= 2)  v += o;
    o = __shfl_up(v, 4);  if (lane >= 4)  v += o;
    o = __shfl_up(v, 8);  if (lane >= 8)  v += o;
    o = __shfl_up(v, 16); if (lane >= 16) v += o;
    o = __shfl_up(v, 32); if (lane >= 32) v += o;
    const float F = v - cell;                             // exclusive prefix = F_ref[lane]
    const float A = 0.5f * (cur - prev) / h;
    const float B = fmaf(-(A + A), mj, prev);
    const float D = fmaf(mj, fmaf(mj, A, -prev), F);
    *reinterpret_cast<float4*>(&co[(lane + 1) * ROWF + 4 * d]) = make_float4(A, B, D, A + A);
  }
  // sentinel rows 0 and 65: (A,B,D,2A) = (0,1,0,0) -> y=xn, dt=1 exactly
  if (tid < 32) {
    const int row = (tid >> 4) ? (NBIN - 1) : 0;
    const int d = tid & 15;
    *reinterpret_cast<float4*>(&co[row * ROWF + 4 * d]) = make_float4(0.f, 1.f, 0.f, 0.f);
  }
  __syncthreads();

  const int tpg = gridDim.x * blockDim.x;
  const float4* __restrict__ x4 = reinterpret_cast<const float4*>(x);
  float4* __restrict__ out4 = reinterpret_cast<float4*>(out);
  const int np16 = npts * DIM;

  const int t0 = blockIdx.x * blockDim.x + tid;

  // one tile: compute + store (hh/dbase shared: tpg is even => parity fixed)
#define COMPUTE_TILE(TT, DBASE, HH, XA, XB, PS)                               \
  {                                                                           \
    const int p_ = (TT) >> 1;                                                 \
    const float vals_[8] = {(XA).x, (XA).y, (XA).z, (XA).w,                   \
                            (XB).x, (XB).y, (XB).z, (XB).w};                  \
    float xn_[8]; int idx_[8];                                                \
    _Pragma("unroll")                                                         \
    for (int j = 0; j < 8; ++j) {                                             \
      const float val_ = vals_[j];                                            \
      xn_[j] = fmaf(val_, 0.01f, 0.5f);                                       \
      const float u_ = fmaf(fabsf(val_), K1, 1.0f);                           \
      const float n_ = __log2f(u_) * INV_L2R;                                 \
      int k_ = 32 + (int)ceilf(copysignf(n_, val_));                          \
      k_ = k_ < 0 ? 0 : (k_ > NBIN - 1 ? NBIN - 1 : k_);                      \
      idx_[j] = k_ * ROWF + (DBASE) + (j << 2);                               \
    }                                                                         \
    float4 cf_[8];                                                            \
    _Pragma("unroll")                                                         \
    for (int j = 0; j < 8; ++j)                                               \
      cf_[j] = *reinterpret_cast<const float4*>(&co[idx_[j]]);                \
    float yv_[8], dt_[8];                                                     \
    _Pragma("unroll")                                                         \
    for (int j = 0; j < 8; ++j) {                                             \
      const float z_ = xn_[j];                                                \
      yv_[j] = fmaf(fmaf(z_, fmaf(z_, cf_[j].x, cf_[j].y), cf_[j].z),         \
                    2.0f * BOUNDF, -BOUNDF);                                  \
      dt_[j] = fmaf(z_, cf_[j].w, cf_[j].y);                                  \
    }                                                                         \
    const float prod_ = ((dt_[0] * dt_[1]) * (dt_[2] * dt_[3])) *             \
                        ((dt_[4] * dt_[5]) * (dt_[6] * dt_[7]));              \
    out4[2 * (TT)]     = make_float4(yv_[0], yv_[1], yv_[2], yv_[3]);         \
    out4[2 * (TT) + 1] = make_float4(yv_[4], yv_[5], yv_[6], yv_[7]);         \
    const float full_ = prod_ * __shfl_xor(prod_, 1);                         \
    const float res_  = (HH) ? ((PS) + __logf(full_)) : ((PS) * full_);       \
    out[np16 + (HH) * npts + p_] = res_;                                      \
  }

  if (npairs == 4 * tpg) {
    // -------- fast path: exactly 4 tiles/thread, fully unrolled --------
    const int t1 = t0 + tpg, t2 = t1 + tpg, t3 = t2 + tpg;
    const int hh = t0 & 1;             // same parity for all 4 tiles
    const int dbase = hh << 5;
    const float* __restrict__ sb = hh ? sldj : pdj;

    // 12 loads issued as one block; sched_barrier keeps them above all compute
    const float4 a0 = x4[2 * t0], a1 = x4[2 * t0 + 1];
    const float4 b0 = x4[2 * t1], b1 = x4[2 * t1 + 1];
    const float4 c0 = x4[2 * t2], c1 = x4[2 * t2 + 1];
    const float4 d0 = x4[2 * t3], d1 = x4[2 * t3 + 1];
    const float ap = sb[t0 >> 1], bp = sb[t1 >> 1];
    const float cp = sb[t2 >> 1], dp = sb[t3 >> 1];
    __builtin_amdgcn_sched_barrier(0);

    COMPUTE_TILE(t0, dbase, hh, a0, a1, ap);
    COMPUTE_TILE(t1, dbase, hh, b0, b1, bp);
    COMPUTE_TILE(t2, dbase, hh, c0, c1, cp);
    COMPUTE_TILE(t3, dbase, hh, d0, d1, dp);
  } else {
    // -------- generic tail path: plain grid-stride --------
    for (int t = t0; t < npairs; t += tpg) {
      const int hh = t & 1;
      const int dbase = hh << 5;
      const float4 xa = x4[2 * t], xb = x4[2 * t + 1];
      const float ps = hh ? sldj[t >> 1] : pdj[t >> 1];
      COMPUTE_TILE(t, dbase, hh, xa, xb, ps);
    }
  }
#undef COMPUTE_TILE
}

extern "C" void kernel_launch(void* const* d_in, const int* in_sizes, int n_in,
                              void* d_out, int out_size, void* d_ws, size_t ws_size,
                              hipStream_t stream) {
  const float* x    = (const float*)d_in[0];
  const float* pdj  = (const float*)d_in[1];
  const float* sldj = (const float*)d_in[2];
  const float* lp   = (const float*)d_in[3];
  const float* mesh = (const float*)d_in[4];
  float* out = (float*)d_out;

  const int npts   = in_sizes[0] / DIM;
  const int npairs = npts * 2;
  const int block  = 256;
  int grid = 2048;
  const int needed = (npairs + block - 1) / block;
  if (needed < grid) grid = needed;

  hipLaunchKernelGGL(nll_kernel, dim3(grid), dim3(block), 0, stream,
                     x, pdj, sldj, lp, mesh, out, npts, npairs);
}